// Round 11
// baseline (583.969 us; speedup 1.0000x reference)
//
#include <hip/hip_runtime.h>
#include <hip/hip_bf16.h>
#include <math.h>

#define NE    8
#define KTOP  2
#define CDIM  1024
#define HDIM  4096
#define NTOK  8192
#define CAPE  1280
#define NSLOT (NTOK * KTOP)

typedef __bf16 bf16x8 __attribute__((ext_vector_type(8)));
typedef __bf16 bf16x4 __attribute__((ext_vector_type(4)));
typedef __bf16 bf16x2 __attribute__((ext_vector_type(2)));
typedef float  f32x4  __attribute__((ext_vector_type(4)));

#define GAS __attribute__((address_space(1)))
#define LAS __attribute__((address_space(3)))

// ---------------------------------------------------------------------------
// Transposing fp32 -> bf16 weight conversion: src [E][R][Cc] -> dst [E][Cc][R]
// ---------------------------------------------------------------------------
__global__ __launch_bounds__(256) void k_transpose_bf16(
    const float* __restrict__ src, __bf16* __restrict__ dst, int R, int Cc)
{
    __shared__ __bf16 T[64][72];           // 72 pad: 144B rows, 16B-aligned
    const int e  = blockIdx.z;
    const int cb = blockIdx.x * 64;
    const int rb = blockIdx.y * 64;
    const int t  = threadIdx.x;
    const int bx = t & 15, by = t >> 4;

    const float* s = src + (size_t)e * R * Cc
                   + (size_t)(rb + by * 4) * Cc + cb + bx * 4;
    float4 m[4];
#pragma unroll
    for (int i = 0; i < 4; ++i)
        m[i] = *(const float4*)(s + (size_t)i * Cc);
#pragma unroll
    for (int j = 0; j < 4; ++j) {
        bf16x4 v;
        v[0] = (__bf16)((&m[0].x)[j]);
        v[1] = (__bf16)((&m[1].x)[j]);
        v[2] = (__bf16)((&m[2].x)[j]);
        v[3] = (__bf16)((&m[3].x)[j]);
        *(bf16x4*)&T[bx * 4 + j][by * 4] = v;   // T[c][r] = src[r][c]
    }
    __syncthreads();
    const int oc = t >> 2, rc = (t & 3) * 16;
    __bf16* d = dst + (size_t)e * R * Cc + (size_t)(cb + oc) * R + rb + rc;
    *(bf16x8*)d       = *(const bf16x8*)&T[oc][rc];
    *(bf16x8*)(d + 8) = *(const bf16x8*)&T[oc][rc + 8];
}

// ---------------------------------------------------------------------------
// Router: fp32 logits -> softmax -> top2 -> normalized gates. 1 wave = 1 token.
// ---------------------------------------------------------------------------
__global__ __launch_bounds__(256) void k_router(
    const float* __restrict__ x, const float* __restrict__ rw,
    const float* __restrict__ rb, float* __restrict__ probs,
    float* __restrict__ gates, int* __restrict__ tidx)
{
    __shared__ float rws[NE * CDIM];
    const int tid = threadIdx.x;
    for (int i = tid; i < NE * CDIM / 4; i += 256)
        ((float4*)rws)[i] = ((const float4*)rw)[i];
    __syncthreads();

    const int wave = tid >> 6, lane = tid & 63;
    const int n = blockIdx.x * 4 + wave;
    const float* xr = x + (size_t)n * CDIM;

    float acc[NE];
#pragma unroll
    for (int e = 0; e < NE; ++e) acc[e] = 0.f;
    for (int j = 0; j < CDIM / 64; ++j) {
        const float xv = xr[j * 64 + lane];
#pragma unroll
        for (int e = 0; e < NE; ++e) acc[e] += xv * rws[e * CDIM + j * 64 + lane];
    }
#pragma unroll
    for (int off = 32; off > 0; off >>= 1) {
#pragma unroll
        for (int e = 0; e < NE; ++e) acc[e] += __shfl_down(acc[e], off);
    }
    if (lane == 0) {
        float mx = -1e30f;
#pragma unroll
        for (int e = 0; e < NE; ++e) { acc[e] += rb[e]; mx = fmaxf(mx, acc[e]); }
        float p[NE], s = 0.f;
#pragma unroll
        for (int e = 0; e < NE; ++e) { p[e] = expf(acc[e] - mx); s += p[e]; }
        const float inv = 1.f / s;
#pragma unroll
        for (int e = 0; e < NE; ++e) { p[e] *= inv; probs[(size_t)n * NE + e] = p[e]; }
        int   i1 = 0;  float v1 = p[0];
        int   i2 = -1; float v2 = -1.f;
#pragma unroll
        for (int e = 1; e < NE; ++e) {
            if (p[e] > v1)      { v2 = v1; i2 = i1; v1 = p[e]; i1 = e; }
            else if (p[e] > v2) { v2 = p[e]; i2 = e; }
        }
        const float gs = 1.f / (v1 + v2);
        gates[n * 2 + 0] = v1 * gs;  gates[n * 2 + 1] = v2 * gs;
        tidx[n * 2 + 0]  = i1;       tidx[n * 2 + 1]  = i2;
    }
}

// ---------------------------------------------------------------------------
// Single-block scan — Hillis-Steele log-scan + tree reduce (replay-proven R10).
// ---------------------------------------------------------------------------
__global__ __launch_bounds__(256) void k_scan(
    const int* __restrict__ tidx, const float* __restrict__ probs,
    int* __restrict__ slot, int* __restrict__ tok, float* __restrict__ d_aux)
{
    __shared__ int   lcnt[256][NE];
    __shared__ float ps[256][NE];
    const int t = threadIdx.x;

    for (int i = t; i < NE * CAPE; i += 256) tok[i] = 0;

    int c8[NE];
#pragma unroll
    for (int e = 0; e < NE; ++e) c8[e] = 0;
    const int per  = NSLOT / 256;   // 64
    const int base = t * per;
    for (int s = 0; s < per; ++s) c8[tidx[base + s]]++;
#pragma unroll
    for (int e = 0; e < NE; ++e) lcnt[t][e] = c8[e];

    float f8[NE];
#pragma unroll
    for (int e = 0; e < NE; ++e) f8[e] = 0.f;
    for (int n = t; n < NTOK; n += 256) {
        const float4 a = *(const float4*)(probs + (size_t)n * NE);
        const float4 b = *(const float4*)(probs + (size_t)n * NE + 4);
        f8[0] += a.x; f8[1] += a.y; f8[2] += a.z; f8[3] += a.w;
        f8[4] += b.x; f8[5] += b.y; f8[6] += b.z; f8[7] += b.w;
    }
#pragma unroll
    for (int e = 0; e < NE; ++e) ps[t][e] = f8[e];

    __syncthreads();

    int run[NE];
#pragma unroll
    for (int e = 0; e < NE; ++e) run[e] = c8[e];
    for (int d = 1; d < 256; d <<= 1) {
        int add[NE];
#pragma unroll
        for (int e = 0; e < NE; ++e) add[e] = (t >= d) ? lcnt[t - d][e] : 0;
        __syncthreads();
#pragma unroll
        for (int e = 0; e < NE; ++e) { run[e] += add[e]; lcnt[t][e] = run[e]; }
        __syncthreads();
    }
    int pre[NE], tot[NE];
#pragma unroll
    for (int e = 0; e < NE; ++e) {
        pre[e] = run[e] - c8[e];
        tot[e] = lcnt[255][e];
    }

    for (int d = 128; d >= 1; d >>= 1) {
        if (t < d) {
#pragma unroll
            for (int e = 0; e < NE; ++e) ps[t][e] += ps[t + d][e];
        }
        __syncthreads();
    }

    for (int s = 0; s < per; ++s) {
        const int sg = base + s;
        const int e  = tidx[sg];
        const int p  = pre[e]++;
        if (p < CAPE) { slot[sg] = e * CAPE + p; tok[e * CAPE + p] = sg >> 1; }
        else          { slot[sg] = -1; }
    }
    if (t == 0) {
        float isum = 0.f, lsum = 0.f, ld[NE];
#pragma unroll
        for (int e = 0; e < NE; ++e) isum += ps[0][e];
#pragma unroll
        for (int e = 0; e < NE; ++e) { ld[e] = fminf((float)tot[e], (float)CAPE); lsum += ld[e]; }
        float aux = 0.f;
#pragma unroll
        for (int e = 0; e < NE; ++e) aux += (ps[0][e] / isum) * (ld[e] / lsum);
        *d_aux = aux * (float)(NE * NE);
    }
}

// ---------------------------------------------------------------------------
// Gather tokens into dense per-expert buffers, fp32 -> bf16.
// ---------------------------------------------------------------------------
__global__ __launch_bounds__(256) void k_gather(
    const float* __restrict__ x, const int* __restrict__ tok,
    __bf16* __restrict__ inp)
{
    const int row = blockIdx.x;
    const int t   = threadIdx.x;
    const int tk  = tok[row];
    const float4 v = ((const float4*)(x + (size_t)tk * CDIM))[t];
    bf16x4 o;
    o[0] = (__bf16)v.x; o[1] = (__bf16)v.y; o[2] = (__bf16)v.z; o[3] = (__bf16)v.w;
    *(bf16x4*)(inp + (size_t)row * CDIM + t * 4) = o;
}

// ---------------------------------------------------------------------------
// 128x128 4-wave MFMA GEMM, B-operand in REGISTERS (direct from L2),
// A-only 32KB double-buffered LDS -> 2 independent blocks/CU.
//   Waves 2Mx2N, wave-tile 64x64, acc[4][4] f32x4.
//   Per K-tile: {load fbNext (8x 16B global, regs, dbuf) ; stage A(T+1) (4x
//   global_load_lds, other buf) ; 8 ds_read fa ; lgkm(4) -> 16 MFMA kh0 ;
//   lgkm(0) -> 16 MFMA kh1 ; vmcnt(0) ; barrier}. One barrier per tile.
//   B panels (512KB-1MB) are L2-resident; 2 waves share each fragment (L1 hit).
//   XOR-swizzle byte^=(row&7)<<4 on A via pre-swizzled source.
//   Epilogue: LDS-bounce (264B stride) -> 256B-contiguous HBM stores.
// ---------------------------------------------------------------------------
#define MFMA_BF16 __builtin_amdgcn_mfma_f32_16x16x32_bf16
#define DSR(dst, addr, IMM) \
    asm volatile("ds_read_b128 %0, %1 offset:" #IMM : "=v"(dst) : "v"(addr))
#define SB0()  __builtin_amdgcn_sched_barrier(0)

#define TILE(BUFO, NBUFO, FBC, FBN, TN)                                       \
    {                                                                         \
        LDB(FBN, TN);                                                         \
        SH_A(NBUFO, TN);                                                      \
        SB0();                                                                \
        DSR(fa0[0], vA0 + (BUFO), 0);    DSR(fa0[1], vA0 + (BUFO), 2048);     \
        DSR(fa0[2], vA0 + (BUFO), 4096); DSR(fa0[3], vA0 + (BUFO), 6144);     \
        DSR(fa1[0], vA1 + (BUFO), 0);    DSR(fa1[1], vA1 + (BUFO), 2048);     \
        DSR(fa1[2], vA1 + (BUFO), 4096); DSR(fa1[3], vA1 + (BUFO), 6144);     \
        asm volatile("s_waitcnt lgkmcnt(4)" ::: "memory"); SB0();             \
        __builtin_amdgcn_s_setprio(1);                                        \
        _Pragma("unroll")                                                     \
        for (int n = 0; n < 4; ++n) {                                         \
            _Pragma("unroll")                                                 \
            for (int m = 0; m < 4; ++m)                                       \
                acc[m][n] = MFMA_BF16(FBC[n][0], fa0[m], acc[m][n], 0,0,0);   \
        }                                                                     \
        __builtin_amdgcn_s_setprio(0);                                        \
        asm volatile("s_waitcnt lgkmcnt(0)" ::: "memory"); SB0();             \
        __builtin_amdgcn_s_setprio(1);                                        \
        _Pragma("unroll")                                                     \
        for (int n = 0; n < 4; ++n) {                                         \
            _Pragma("unroll")                                                 \
            for (int m = 0; m < 4; ++m)                                       \
                acc[m][n] = MFMA_BF16(FBC[n][1], fa1[m], acc[m][n], 0,0,0);   \
        }                                                                     \
        __builtin_amdgcn_s_setprio(0);                                        \
        asm volatile("s_waitcnt vmcnt(0)" ::: "memory");                      \
        __builtin_amdgcn_s_barrier();                                         \
        SB0();                                                                \
    }

template <bool GELU>
__global__ __launch_bounds__(256, 2) void k_gemmR(
    const __bf16* __restrict__ Aall, const __bf16* __restrict__ Ball,
    const float* __restrict__ biasAll, __bf16* __restrict__ Call,
    int Ktot, int Ntot, int NBN, int mtPerE)
{
    __shared__ char lds[34048];   // A dbuf 2x16KB @0; epilogue reuses 33.8KB

    const int NK  = Ktot >> 6;
    const int cpx = gridDim.x >> 3;                 // grid % 8 == 0 by caller
    const int id  = blockIdx.x;
    const int sid = (id & 7) * cpx + (id >> 3);     // bijective XCD swizzle
    const int bm  = sid / NBN, bn = sid % NBN;
    const int e   = bm / mtPerE;

    const size_t row0 = (size_t)bm * 128;
    const int    col0 = bn * 128;

    const int tid = threadIdx.x;
    const int w   = tid >> 6, l = tid & 63;
    const int wm  = w >> 1, wn = w & 1;             // 2M x 2N, wave 64x64
    const int lr  = l & 15, hi = l >> 4;

    // ---- A staging: wave w instr j covers rows w*32 + j*8 + (l>>3) ----
    const int arow = w * 32 + (l >> 3);
    const int kf   = ((l & 7) ^ (l >> 3)) << 3;     // pre-swizzled k elems
    const __bf16* pA = Aall + (row0 + arow) * (size_t)Ktot + kf;
    const unsigned L0 = (unsigned)(size_t)(LAS char*)lds;
    const unsigned dA = L0 + w * 4096;              // HW adds lane*16

    auto SH_A = [&](unsigned bo, int kt) {
        const __bf16* g = pA + (size_t)kt * 64;
#pragma unroll
        for (int j = 0; j < 4; ++j)
            __builtin_amdgcn_global_load_lds(
                (const GAS void*)(g + (size_t)j * 8 * Ktot),
                (LAS void*)(size_t)(dA + bo + j * 1024), 16, 0, 0);
    };

    // ---- B direct-from-global fragment base: row = col0 + wn*64 + n*16 + lr ----
    const __bf16* pB = Ball
        + ((size_t)e * Ntot + col0 + wn * 64 + lr) * (size_t)Ktot + hi * 8;

    auto LDB = [&](bf16x8 (&fb)[4][2], int kt) {
#pragma unroll
        for (int n = 0; n < 4; ++n) {
#pragma unroll
            for (int kh = 0; kh < 2; ++kh)
                fb[n][kh] = *(const bf16x8*)(pB + (size_t)n * 16 * Ktot
                                             + kt * 64 + kh * 32);
        }
    };

    // ---- A ds_read bases (swizzled) ----
    const unsigned swz = (l & 7) << 4;
    const unsigned kb0 = ((unsigned)(hi << 4)) ^ swz;        // k-half 0
    const unsigned kb1 = ((unsigned)(64 + (hi << 4))) ^ swz; // k-half 1
    const unsigned vA0 = L0 + (unsigned)((wm * 64 + lr) * 128) + kb0;
    const unsigned vA1 = L0 + (unsigned)((wm * 64 + lr) * 128) + kb1;

    bf16x8 fbX[4][2], fbY[4][2];
    // ---- prologue: A(0) -> buf0, fbX(0) ----
    SH_A(0u, 0);
    LDB(fbX, 0);
    asm volatile("s_waitcnt vmcnt(0)" ::: "memory");
    __builtin_amdgcn_s_barrier();
    SB0();

    f32x4 acc[4][4] = {};
    bf16x8 fa0[4], fa1[4];

    for (int T = 0; T < NK; T += 2) {
        const int t1 = (T + 1 < NK) ? T + 1 : NK - 1;   // tail: re-fetch, unused
        const int t2 = (T + 2 < NK) ? T + 2 : NK - 1;
        TILE(0u,     16384u, fbX, fbY, t1)
        TILE(16384u, 0u,     fbY, fbX, t2)
    }

    // ---- epilogue: bias+GELU, LDS bounce (264B stride), coalesced stores ----
    const int lrow0 = wm * 64, lcol0 = wn * 64;
#pragma unroll
    for (int n = 0; n < 4; ++n) {
        float bbv[4] = {0.f, 0.f, 0.f, 0.f};
        if (GELU) {
            const float4 b4 = *(const float4*)(biasAll + (size_t)e * Ntot
                                               + col0 + lcol0 + n * 16 + hi * 4);
            bbv[0] = b4.x; bbv[1] = b4.y; bbv[2] = b4.z; bbv[3] = b4.w;
        }
#pragma unroll
        for (int m = 0; m < 4; ++m) {
            const f32x4 v = acc[m][n];
            bf16x4 o;
#pragma unroll
            for (int i = 0; i < 4; ++i) {
                float t = v[i];
                if (GELU) {
                    t += bbv[i];
                    const float u  = 0.7978845608028654f * (t + 0.044715f * t * t * t);
                    const float ex = __expf(2.f * u);
                    t = t * (1.f - 1.f / (ex + 1.f));   // 0.5t(1+tanh u)
                }
                o[i] = (__bf16)t;
            }
            *(bf16x4*)(lds + (lrow0 + m * 16 + lr) * 264
                           + (lcol0 + n * 16 + hi * 4) * 2) = o;
        }
    }
    __builtin_amdgcn_s_barrier();
#pragma unroll
    for (int it = 0; it < 8; ++it) {
        const int rr = it * 16 + (tid >> 4);
        const int cc = (tid & 15) * 8;
        const bf16x8 v = *(const bf16x8*)(lds + rr * 264 + cc * 2);
        *(bf16x8*)(Call + (row0 + rr) * (size_t)Ntot + col0 + cc) = v;
    }
}

// ---------------------------------------------------------------------------
// Combine: y[n][c] = sum_k gate * (out[slot][c] + b2[e][c]); writes all of y.
// ---------------------------------------------------------------------------
__global__ __launch_bounds__(256) void k_combine(
    const __bf16* __restrict__ outb, const int* __restrict__ slot,
    const float* __restrict__ gates, const int* __restrict__ tidx,
    const float* __restrict__ b2, float* __restrict__ y)
{
    const int n = blockIdx.x;
    const int t = threadIdx.x;
    const int c = t * 4;
    float r0 = 0.f, r1 = 0.f, r2 = 0.f, r3 = 0.f;
#pragma unroll
    for (int k = 0; k < KTOP; ++k) {
        const int s = slot[n * 2 + k];
        if (s < 0) continue;
        const float g = gates[n * 2 + k];
        const int   e = tidx[n * 2 + k];
        const bf16x4 v = *(const bf16x4*)(outb + (size_t)s * CDIM + c);
        const float4 bb = *(const float4*)(b2 + (size_t)e * CDIM + c);
        r0 += g * ((float)v[0] + bb.x);
        r1 += g * ((float)v[1] + bb.y);
        r2 += g * ((float)v[2] + bb.z);
        r3 += g * ((float)v[3] + bb.w);
    }
    float4 o = make_float4(r0, r1, r2, r3);
    *(float4*)(y + (size_t)n * CDIM + c) = o;
}

// ---------------------------------------------------------------------------
extern "C" void kernel_launch(void* const* d_in, const int* in_sizes, int n_in,
                              void* d_out, int out_size, void* d_ws, size_t ws_size,
                              hipStream_t stream)
{
    const float* x  = (const float*)d_in[0];
    const float* rw = (const float*)d_in[1];
    const float* rb = (const float*)d_in[2];
    const float* w1 = (const float*)d_in[3];
    const float* b1 = (const float*)d_in[4];
    const float* w2 = (const float*)d_in[5];
    const float* b2 = (const float*)d_in[6];
    float* y = (float*)d_out;

    char* ws = (char*)d_ws;
    size_t off = 0;
    auto alloc = [&](size_t bytes) -> void* {
        void* p = ws + off;
        off = (off + bytes + 255) & ~(size_t)255;
        return p;
    };
    __bf16* w1t  = (__bf16*)alloc((size_t)NE * CDIM * HDIM * 2);   // [E][H][C]
    __bf16* w2t  = (__bf16*)alloc((size_t)NE * CDIM * HDIM * 2);   // [E][C][H]
    __bf16* inp  = (__bf16*)alloc((size_t)NE * CAPE * CDIM * 2);   // [E*cap][C]
    __bf16* hbuf = (__bf16*)alloc((size_t)NE * CAPE * HDIM * 2);   // [E*cap][H]
    __bf16* outb = (__bf16*)alloc((size_t)NE * CAPE * CDIM * 2);   // [E*cap][C]
    float*  probs = (float*)alloc((size_t)NTOK * NE * 4);
    float*  gates = (float*)alloc((size_t)NTOK * 2 * 4);
    int*    tidx  = (int*)alloc((size_t)NTOK * 2 * 4);
    int*    slot  = (int*)alloc((size_t)NTOK * 2 * 4);
    int*    tok   = (int*)alloc((size_t)NE * CAPE * 4);

    // 1. weight conversion (transposed to B^T layout, bf16)
    k_transpose_bf16<<<dim3(HDIM / 64, CDIM / 64, NE), 256, 0, stream>>>(
        w1, w1t, CDIM, HDIM);
    k_transpose_bf16<<<dim3(CDIM / 64, HDIM / 64, NE), 256, 0, stream>>>(
        w2, w2t, HDIM, CDIM);

    // 2. router
    k_router<<<NTOK / 4, 256, 0, stream>>>(x, rw, rb, probs, gates, tidx);

    // 3. dispatch scan + aux loss (single block, log-scan)
    k_scan<<<1, 256, 0, stream>>>(tidx, probs, slot, tok, y + (size_t)NTOK * CDIM);

    // 4. gather expert inputs (bf16)
    k_gather<<<NE * CAPE, 256, 0, stream>>>(x, tok, inp);

    // 5. expert FFN — 128^2 4-wave B-in-regs GEMMs, 2 blocks/CU
    //    GEMM1: 80 x 32 = 2560 blocks
    k_gemmR<true><<<dim3((NE * CAPE / 128) * (HDIM / 128)), 256, 0, stream>>>(
        inp, w1t, b1, hbuf, CDIM, HDIM, HDIM / 128, CAPE / 128);
    //    GEMM2: 80 x 8 = 640 blocks
    k_gemmR<false><<<dim3((NE * CAPE / 128) * (CDIM / 128)), 256, 0, stream>>>(
        hbuf, w2t, nullptr, outb, HDIM, CDIM, CDIM / 128, CAPE / 128);

    // 6. combine back to tokens (+aux already written by scan)
    k_combine<<<NTOK, 256, 0, stream>>>(outb, slot, gates, tidx, b2, y);
}

// Round 12
// 373.532 us; speedup vs baseline: 1.5634x; 1.5634x over previous
//
#include <hip/hip_runtime.h>
#include <hip/hip_bf16.h>
#include <math.h>

#define NE    8
#define KTOP  2
#define CDIM  1024
#define HDIM  4096
#define NTOK  8192
#define CAPE  1280
#define NSLOT (NTOK * KTOP)

typedef __bf16 bf16x8 __attribute__((ext_vector_type(8)));
typedef __bf16 bf16x4 __attribute__((ext_vector_type(4)));
typedef float  f32x4  __attribute__((ext_vector_type(4)));

#define GAS __attribute__((address_space(1)))
#define LAS __attribute__((address_space(3)))

// ---------------------------------------------------------------------------
// Fused prolog: w1 transpose + w2 transpose + router in ONE launch.
//   blocks [0,8192):      w1 [E][C][H] -> w1t [E][H][C]   (R=1024, Cc=4096)
//   blocks [8192,16384):  w2 [E][H][C] -> w2t [E][C][H]   (R=4096, Cc=1024)
//   blocks [16384,18432): router, 4 tokens/block
// Transpose body: 64x64 tile, 4x4 register blocklet, bf16x8 coalesced stores.
// ---------------------------------------------------------------------------
__device__ __forceinline__ void transpose64_body(
    const float* __restrict__ src, __bf16* __restrict__ dst, int R, int Cc,
    int bx, int by, int e, int t, char* sm)
{
    __bf16 (*T)[72] = (__bf16(*)[72])sm;
    const int cb = bx * 64;
    const int rb = by * 64;
    const int px = t & 15, py = t >> 4;

    const float* s = src + (size_t)e * R * Cc
                   + (size_t)(rb + py * 4) * Cc + cb + px * 4;
    float4 m[4];
#pragma unroll
    for (int i = 0; i < 4; ++i)
        m[i] = *(const float4*)(s + (size_t)i * Cc);
#pragma unroll
    for (int j = 0; j < 4; ++j) {
        bf16x4 v;
        v[0] = (__bf16)((&m[0].x)[j]);
        v[1] = (__bf16)((&m[1].x)[j]);
        v[2] = (__bf16)((&m[2].x)[j]);
        v[3] = (__bf16)((&m[3].x)[j]);
        *(bf16x4*)&T[px * 4 + j][py * 4] = v;   // T[c][r] = src[r][c]
    }
    __syncthreads();
    const int oc = t >> 2, rc = (t & 3) * 16;
    __bf16* d = dst + (size_t)e * R * Cc + (size_t)(cb + oc) * R + rb + rc;
    *(bf16x8*)d       = *(const bf16x8*)&T[oc][rc];
    *(bf16x8*)(d + 8) = *(const bf16x8*)&T[oc][rc + 8];
}

__global__ __launch_bounds__(256) void k_prolog(
    const float* __restrict__ w1, const float* __restrict__ w2,
    const float* __restrict__ x, const float* __restrict__ rw,
    const float* __restrict__ rb,
    __bf16* __restrict__ w1t, __bf16* __restrict__ w2t,
    float* __restrict__ probs, float* __restrict__ gates,
    int* __restrict__ tidx)
{
    __shared__ char sm[32768];     // transpose: 9216B; router: 32KB
    const int bid = blockIdx.x;
    const int t   = threadIdx.x;

    if (bid < 8192) {              // w1: R=CDIM, Cc=HDIM (64 x 16 x 8)
        const int bx = bid & 63, by = (bid >> 6) & 15, e = bid >> 10;
        transpose64_body(w1, w1t, CDIM, HDIM, bx, by, e, t, sm);
        return;
    }
    if (bid < 16384) {             // w2: R=HDIM, Cc=CDIM (16 x 64 x 8)
        const int b2 = bid - 8192;
        const int bx = b2 & 15, by = (b2 >> 4) & 63, e = b2 >> 10;
        transpose64_body(w2, w2t, HDIM, CDIM, bx, by, e, t, sm);
        return;
    }

    // ---- router ----
    float* rws = (float*)sm;
    for (int i = t; i < NE * CDIM / 4; i += 256)
        ((float4*)rws)[i] = ((const float4*)rw)[i];
    __syncthreads();

    const int wave = t >> 6, lane = t & 63;
    const int n = (bid - 16384) * 4 + wave;
    const float* xr = x + (size_t)n * CDIM;

    float acc[NE];
#pragma unroll
    for (int e = 0; e < NE; ++e) acc[e] = 0.f;
    for (int j = 0; j < CDIM / 64; ++j) {
        const float xv = xr[j * 64 + lane];
#pragma unroll
        for (int e = 0; e < NE; ++e) acc[e] += xv * rws[e * CDIM + j * 64 + lane];
    }
#pragma unroll
    for (int off = 32; off > 0; off >>= 1) {
#pragma unroll
        for (int e = 0; e < NE; ++e) acc[e] += __shfl_down(acc[e], off);
    }
    if (lane == 0) {
        float mx = -1e30f;
#pragma unroll
        for (int e = 0; e < NE; ++e) { acc[e] += rb[e]; mx = fmaxf(mx, acc[e]); }
        float p[NE], s = 0.f;
#pragma unroll
        for (int e = 0; e < NE; ++e) { p[e] = expf(acc[e] - mx); s += p[e]; }
        const float inv = 1.f / s;
#pragma unroll
        for (int e = 0; e < NE; ++e) { p[e] *= inv; probs[(size_t)n * NE + e] = p[e]; }
        int   i1 = 0;  float v1 = p[0];
        int   i2 = -1; float v2 = -1.f;
#pragma unroll
        for (int e = 1; e < NE; ++e) {
            if (p[e] > v1)      { v2 = v1; i2 = i1; v1 = p[e]; i1 = e; }
            else if (p[e] > v2) { v2 = p[e]; i2 = e; }
        }
        const float gs = 1.f / (v1 + v2);
        gates[n * 2 + 0] = v1 * gs;  gates[n * 2 + 1] = v2 * gs;
        tidx[n * 2 + 0]  = i1;       tidx[n * 2 + 1]  = i2;
    }
}

// ---------------------------------------------------------------------------
// Single-block scan — Hillis-Steele log-scan + tree reduce (replay-proven R10).
// ---------------------------------------------------------------------------
__global__ __launch_bounds__(256) void k_scan(
    const int* __restrict__ tidx, const float* __restrict__ probs,
    int* __restrict__ slot, int* __restrict__ tok, float* __restrict__ d_aux)
{
    __shared__ int   lcnt[256][NE];
    __shared__ float ps[256][NE];
    const int t = threadIdx.x;

    for (int i = t; i < NE * CAPE; i += 256) tok[i] = 0;

    int c8[NE];
#pragma unroll
    for (int e = 0; e < NE; ++e) c8[e] = 0;
    const int per  = NSLOT / 256;   // 64
    const int base = t * per;
    for (int s = 0; s < per; ++s) c8[tidx[base + s]]++;
#pragma unroll
    for (int e = 0; e < NE; ++e) lcnt[t][e] = c8[e];

    float f8[NE];
#pragma unroll
    for (int e = 0; e < NE; ++e) f8[e] = 0.f;
    for (int n = t; n < NTOK; n += 256) {
        const float4 a = *(const float4*)(probs + (size_t)n * NE);
        const float4 b = *(const float4*)(probs + (size_t)n * NE + 4);
        f8[0] += a.x; f8[1] += a.y; f8[2] += a.z; f8[3] += a.w;
        f8[4] += b.x; f8[5] += b.y; f8[6] += b.z; f8[7] += b.w;
    }
#pragma unroll
    for (int e = 0; e < NE; ++e) ps[t][e] = f8[e];

    __syncthreads();

    int run[NE];
#pragma unroll
    for (int e = 0; e < NE; ++e) run[e] = c8[e];
    for (int d = 1; d < 256; d <<= 1) {
        int add[NE];
#pragma unroll
        for (int e = 0; e < NE; ++e) add[e] = (t >= d) ? lcnt[t - d][e] : 0;
        __syncthreads();
#pragma unroll
        for (int e = 0; e < NE; ++e) { run[e] += add[e]; lcnt[t][e] = run[e]; }
        __syncthreads();
    }
    int pre[NE], tot[NE];
#pragma unroll
    for (int e = 0; e < NE; ++e) {
        pre[e] = run[e] - c8[e];
        tot[e] = lcnt[255][e];
    }

    for (int d = 128; d >= 1; d >>= 1) {
        if (t < d) {
#pragma unroll
            for (int e = 0; e < NE; ++e) ps[t][e] += ps[t + d][e];
        }
        __syncthreads();
    }

    for (int s = 0; s < per; ++s) {
        const int sg = base + s;
        const int e  = tidx[sg];
        const int p  = pre[e]++;
        if (p < CAPE) { slot[sg] = e * CAPE + p; tok[e * CAPE + p] = sg >> 1; }
        else          { slot[sg] = -1; }
    }
    if (t == 0) {
        float isum = 0.f, lsum = 0.f, ld[NE];
#pragma unroll
        for (int e = 0; e < NE; ++e) isum += ps[0][e];
#pragma unroll
        for (int e = 0; e < NE; ++e) { ld[e] = fminf((float)tot[e], (float)CAPE); lsum += ld[e]; }
        float aux = 0.f;
#pragma unroll
        for (int e = 0; e < NE; ++e) aux += (ps[0][e] / isum) * (ld[e] / lsum);
        *d_aux = aux * (float)(NE * NE);
    }
}

// ---------------------------------------------------------------------------
// Gather tokens into dense per-expert buffers, fp32 -> bf16.
// ---------------------------------------------------------------------------
__global__ __launch_bounds__(256) void k_gather(
    const float* __restrict__ x, const int* __restrict__ tok,
    __bf16* __restrict__ inp)
{
    const int row = blockIdx.x;
    const int t   = threadIdx.x;
    const int tk  = tok[row];
    const float4 v = ((const float4*)(x + (size_t)tk * CDIM))[t];
    bf16x4 o;
    o[0] = (__bf16)v.x; o[1] = (__bf16)v.y; o[2] = (__bf16)v.z; o[3] = (__bf16)v.w;
    *(bf16x4*)(inp + (size_t)row * CDIM + t * 4) = o;
}

// ---------------------------------------------------------------------------
// 256x256 8-wave MFMA GEMM — m201 8-phase structure + LDS-bounce epilogue
// (replay-proven R10; byte-identical).
// ---------------------------------------------------------------------------
#define MFMA_BF16 __builtin_amdgcn_mfma_f32_16x16x32_bf16
#define DSR_I(dst, addr, IMM) \
    asm volatile("ds_read_b128 %0, %1 offset:" #IMM : "=v"(dst) : "v"(addr))
#define DSR(dst, addr, IMM) DSR_I(dst, addr, IMM)
#define WVM4() asm volatile("s_waitcnt vmcnt(4)" ::: "memory")
#define SB0()  __builtin_amdgcn_sched_barrier(0)

#define PH(RDB, OA0, OA1, MB, VA0, VA1, VB0, VB1, STG, VMW)                   \
    {                                                                         \
        if (RDB) {                                                            \
            DSR(fb[0][0], VB0, 0);    DSR(fb[0][1], VB1, 0);                  \
            DSR(fb[1][0], VB0, 2048); DSR(fb[1][1], VB1, 2048);               \
            DSR(fb[2][0], VB0, 4096); DSR(fb[2][1], VB1, 4096);               \
            DSR(fb[3][0], VB0, 6144); DSR(fb[3][1], VB1, 6144);               \
        }                                                                     \
        DSR(fa[0][0], VA0, OA0); DSR(fa[0][1], VA1, OA0);                     \
        DSR(fa[1][0], VA0, OA1); DSR(fa[1][1], VA1, OA1);                     \
        STG;                                                                  \
        if (RDB) { asm volatile("s_waitcnt lgkmcnt(8)" ::: "memory"); }       \
        __builtin_amdgcn_s_barrier();                                         \
        asm volatile("s_waitcnt lgkmcnt(0)" ::: "memory");                    \
        SB0();                                                                \
        __builtin_amdgcn_s_setprio(1);                                        \
        _Pragma("unroll")                                                     \
        for (int n = 0; n < 4; ++n) {                                         \
            acc[MB][n]   = MFMA_BF16(fb[n][0], fa[0][0], acc[MB][n], 0,0,0);  \
            acc[MB][n]   = MFMA_BF16(fb[n][1], fa[0][1], acc[MB][n], 0,0,0);  \
            acc[MB+1][n] = MFMA_BF16(fb[n][0], fa[1][0], acc[MB+1][n],0,0,0); \
            acc[MB+1][n] = MFMA_BF16(fb[n][1], fa[1][1], acc[MB+1][n],0,0,0); \
        }                                                                     \
        __builtin_amdgcn_s_setprio(0);                                        \
        VMW;                                                                  \
        __builtin_amdgcn_s_barrier();                                        \
        SB0();                                                                \
    }

template <bool GELU>
__global__ __launch_bounds__(512, 2) void k_gemm8(
    const __bf16* __restrict__ Aall, const __bf16* __restrict__ Ball,
    const float* __restrict__ biasAll, __bf16* __restrict__ Call,
    int Ktot, int Ntot, int NBN, int mtPerE)
{
    __shared__ char lds[133120];   // K-loop: A @0..64K, B @64K..128K; epi: 256x520B

    const int NK  = Ktot >> 6;
    const int NI  = NK >> 1;
    const int cpx = gridDim.x >> 3;                 // grid % 8 == 0 by caller
    const int id  = blockIdx.x;
    const int sid = (id & 7) * cpx + (id >> 3);     // bijective XCD swizzle
    const int bm  = sid / NBN, bn = sid % NBN;
    const int e   = bm / mtPerE;

    const size_t row0 = (size_t)bm * 256;
    const int    col0 = bn * 256;

    const int tid = threadIdx.x;
    const int w   = tid >> 6, l = tid & 63;
    const int wr  = w >> 2, wc = w & 3;             // 2M x 4N wave grid
    const int lr  = l & 15, hi = l >> 4;

    const int srow = tid >> 3;                              // 0..63
    const int kf   = ((tid & 7) ^ (srow & 7)) << 3;         // swizzled k elems
    const __bf16* pA = Aall + (row0 + srow) * (size_t)Ktot + kf;
    const __bf16* pB = Ball + ((size_t)e * Ntot + col0 + srow) * (size_t)Ktot + kf;
    const unsigned L0 = (unsigned)(size_t)(LAS char*)lds;

    const unsigned sA00 = L0 +          w * 1024;
    const unsigned sA01 = sA00 + 16384;
    const unsigned sA10 = sA00 + 32768;
    const unsigned sA11 = sA00 + 49152;
    const unsigned sB00 = sA00 + 65536;
    const unsigned sB01 = sB00 + 16384;
    const unsigned sB10 = sB00 + 32768;
    const unsigned sB11 = sB00 + 49152;

    auto SH_A = [&](unsigned dbase, int half, int kt) {
        const __bf16* g = pA + (size_t)(half * 128) * Ktot + (size_t)kt * 64;
#pragma unroll
        for (int gg = 0; gg < 2; ++gg)
            __builtin_amdgcn_global_load_lds(
                (const GAS void*)(g + (size_t)gg * 64 * Ktot),
                (LAS void*)(size_t)(dbase + gg * 8192), 16, 0, 0);
    };
    auto SH_B = [&](unsigned dbase, int half, int kt) {
        const __bf16* g = pB + (size_t)(half * 128) * Ktot + (size_t)kt * 64;
#pragma unroll
        for (int gg = 0; gg < 2; ++gg)
            __builtin_amdgcn_global_load_lds(
                (const GAS void*)(g + (size_t)gg * 64 * Ktot),
                (LAS void*)(size_t)(dbase + gg * 8192), 16, 0, 0);
    };

    const unsigned swz = (l & 7) << 4;
    const unsigned kb0 = ((unsigned)(hi << 4)) ^ swz;
    const unsigned kb1 = ((unsigned)(64 + (hi << 4))) ^ swz;
    const unsigned vA00 = L0 + (unsigned)(wr * 16384 + lr * 128) + kb0;
    const unsigned vA01 = L0 + (unsigned)(wr * 16384 + lr * 128) + kb1;
    const unsigned vA10 = vA00 + 32768, vA11 = vA01 + 32768;
    const unsigned vBb  = L0 + 65536
        + (unsigned)((wc >> 1) * 16384 + ((wc & 1) * 64 + lr) * 128);
    const unsigned vB00 = vBb + kb0, vB01 = vBb + kb1;
    const unsigned vB10 = vB00 + 32768, vB11 = vB01 + 32768;

    SH_B(sB00, 0, 0); SH_B(sB01, 1, 0);
    SH_A(sA00, 0, 0); SH_A(sA01, 1, 0);
    SH_B(sB10, 0, 1); SH_B(sB11, 1, 1);
    WVM4();
    __builtin_amdgcn_s_barrier();
    SB0();

    f32x4 acc[8][4] = {};
    bf16x8 fa[2][2], fb[4][2];

    for (int i = 0; i < NI; ++i) {
        const int t1 = 2 * i + 1;
        const int t2 = (2 * i + 2 < NK) ? 2 * i + 2 : NK - 1;
        const int t3 = (2 * i + 3 < NK) ? 2 * i + 3 : NK - 1;
        PH(1, 0,     2048,  0, vA00, vA01, vB00, vB01, SH_A(sA10, 0, t1), (void)0)
        PH(0, 4096,  6144,  2, vA00, vA01, vB00, vB01, SH_A(sA11, 1, t1), (void)0)
        PH(0, 8192,  10240, 4, vA00, vA01, vB00, vB01, SH_B(sB00, 0, t2), (void)0)
        PH(0, 12288, 14336, 6, vA00, vA01, vB00, vB01, SH_B(sB01, 1, t2), WVM4())
        PH(1, 0,     2048,  0, vA10, vA11, vB10, vB11, SH_A(sA00, 0, t2), (void)0)
        PH(0, 4096,  6144,  2, vA10, vA11, vB10, vB11, SH_A(sA01, 1, t2), (void)0)
        PH(0, 8192,  10240, 4, vA10, vA11, vB10, vB11, SH_B(sB10, 0, t3), (void)0)
        PH(0, 12288, 14336, 6, vA10, vA11, vB10, vB11, SH_B(sB11, 1, t3), WVM4())
    }

    // ---- epilogue: drain tail staging, then LDS-bounce coalesced stores ----
    asm volatile("s_waitcnt vmcnt(0)" ::: "memory");
    __builtin_amdgcn_s_barrier();
    SB0();

    const int lrow0 = wr * 128;
    const int lcol0 = wc * 64;
#pragma unroll
    for (int n = 0; n < 4; ++n) {
        float bbv[4] = {0.f, 0.f, 0.f, 0.f};
        if (GELU) {
            const float4 b4 = *(const float4*)(biasAll + (size_t)e * Ntot
                                               + col0 + lcol0 + n * 16 + hi * 4);
            bbv[0] = b4.x; bbv[1] = b4.y; bbv[2] = b4.z; bbv[3] = b4.w;
        }
#pragma unroll
        for (int m = 0; m < 8; ++m) {
            const f32x4 v = acc[m][n];
            bf16x4 o;
#pragma unroll
            for (int i = 0; i < 4; ++i) {
                float t = v[i];
                if (GELU) {
                    t += bbv[i];
                    const float u  = 0.7978845608028654f * (t + 0.044715f * t * t * t);
                    const float ex = __expf(2.f * u);
                    t = t * (1.f - 1.f / (ex + 1.f));   // 0.5t(1+tanh u)
                }
                o[i] = (__bf16)t;
            }
            *(bf16x4*)(lds + (lrow0 + m * 16 + lr) * 520
                           + (lcol0 + n * 16 + hi * 4) * 2) = o;
        }
    }
    __builtin_amdgcn_s_barrier();

    {
        const int rr0 = tid >> 5;               // 0..15
        const int cc  = (tid & 31) * 8;         // col elems, 16B per lane
#pragma unroll
        for (int it = 0; it < 16; ++it) {
            const int rr = it * 16 + rr0;
            const bf16x8 v = *(const bf16x8*)(lds + rr * 520 + cc * 2);
            *(bf16x8*)(Call + (row0 + rr) * (size_t)Ntot + col0 + cc) = v;
        }
    }
}

// ---------------------------------------------------------------------------
// Combine: y[n][c] = sum_k gate * (out[slot][c] + b2[e][c]); writes all of y.
// ---------------------------------------------------------------------------
__global__ __launch_bounds__(256) void k_combine(
    const __bf16* __restrict__ outb, const int* __restrict__ slot,
    const float* __restrict__ gates, const int* __restrict__ tidx,
    const float* __restrict__ b2, float* __restrict__ y)
{
    const int n = blockIdx.x;
    const int t = threadIdx.x;
    const int c = t * 4;
    float r0 = 0.f, r1 = 0.f, r2 = 0.f, r3 = 0.f;
#pragma unroll
    for (int k = 0; k < KTOP; ++k) {
        const int s = slot[n * 2 + k];
        if (s < 0) continue;
        const float g = gates[n * 2 + k];
        const int   e = tidx[n * 2 + k];
        const bf16x4 v = *(const bf16x4*)(outb + (size_t)s * CDIM + c);
        const float4 bb = *(const float4*)(b2 + (size_t)e * CDIM + c);
        r0 += g * ((float)v[0] + bb.x);
        r1 += g * ((float)v[1] + bb.y);
        r2 += g * ((float)v[2] + bb.z);
        r3 += g * ((float)v[3] + bb.w);
    }
    float4 o = make_float4(r0, r1, r2, r3);
    *(float4*)(y + (size_t)n * CDIM + c) = o;
}

// ---------------------------------------------------------------------------
extern "C" void kernel_launch(void* const* d_in, const int* in_sizes, int n_in,
                              void* d_out, int out_size, void* d_ws, size_t ws_size,
                              hipStream_t stream)
{
    const float* x  = (const float*)d_in[0];
    const float* rw = (const float*)d_in[1];
    const float* rb = (const float*)d_in[2];
    const float* w1 = (const float*)d_in[3];
    const float* b1 = (const float*)d_in[4];
    const float* w2 = (const float*)d_in[5];
    const float* b2 = (const float*)d_in[6];
    float* y = (float*)d_out;

    char* ws = (char*)d_ws;
    size_t off = 0;
    auto alloc = [&](size_t bytes) -> void* {
        void* p = ws + off;
        off = (off + bytes + 255) & ~(size_t)255;
        return p;
    };
    __bf16* w1t  = (__bf16*)alloc((size_t)NE * CDIM * HDIM * 2);   // [E][H][C]
    __bf16* w2t  = (__bf16*)alloc((size_t)NE * CDIM * HDIM * 2);   // [E][C][H]
    __bf16* inp  = (__bf16*)alloc((size_t)NE * CAPE * CDIM * 2);   // [E*cap][C]
    __bf16* hbuf = (__bf16*)alloc((size_t)NE * CAPE * HDIM * 2);   // [E*cap][H]
    __bf16* outb = (__bf16*)alloc((size_t)NE * CAPE * CDIM * 2);   // [E*cap][C]
    float*  probs = (float*)alloc((size_t)NTOK * NE * 4);
    float*  gates = (float*)alloc((size_t)NTOK * 2 * 4);
    int*    tidx  = (int*)alloc((size_t)NTOK * 2 * 4);
    int*    slot  = (int*)alloc((size_t)NTOK * 2 * 4);
    int*    tok   = (int*)alloc((size_t)NE * CAPE * 4);

    // 1. fused prolog: w1 transpose + w2 transpose + router (one launch)
    k_prolog<<<8192 + 8192 + NTOK / 4, 256, 0, stream>>>(
        w1, w2, x, rw, rb, w1t, w2t, probs, gates, tidx);

    // 2. dispatch scan + aux loss (single block, log-scan)
    k_scan<<<1, 256, 0, stream>>>(tidx, probs, slot, tok, y + (size_t)NTOK * CDIM);

    // 3. gather expert inputs (bf16)
    k_gather<<<NE * CAPE, 256, 0, stream>>>(x, tok, inp);

    // 4. expert FFN — 256^2 8-wave 8-phase MFMA GEMMs + coalesced epilogue
    k_gemm8<true><<<dim3((NE * CAPE / 256) * (HDIM / 256)), 512, 0, stream>>>(
        inp, w1t, b1, hbuf, CDIM, HDIM, HDIM / 256, CAPE / 256);
    k_gemm8<false><<<dim3((NE * CAPE / 256) * (CDIM / 256)), 512, 0, stream>>>(
        hbuf, w2t, nullptr, outb, HDIM, CDIM, CDIM / 256, CAPE / 256);

    // 5. combine back to tokens (+aux already written by scan)
    k_combine<<<NTOK, 256, 0, stream>>>(outb, slot, gates, tidx, b2, y);
}

// Round 13
// 354.699 us; speedup vs baseline: 1.6464x; 1.0531x over previous
//
#include <hip/hip_runtime.h>
#include <hip/hip_bf16.h>
#include <math.h>

#define NE    8
#define KTOP  2
#define CDIM  1024
#define HDIM  4096
#define NTOK  8192
#define CAPE  1280
#define NSLOT (NTOK * KTOP)
#define G1BLK 640            // GEMM1 sub-grid in the fused launch (640 % 8 == 0)

typedef __bf16 bf16x8 __attribute__((ext_vector_type(8)));
typedef __bf16 bf16x4 __attribute__((ext_vector_type(4)));
typedef float  f32x4  __attribute__((ext_vector_type(4)));

#define GAS __attribute__((address_space(1)))
#define LAS __attribute__((address_space(3)))

// ---------------------------------------------------------------------------
// Transpose body: 64x64 tile, 4x4 register blocklet, bf16x8 coalesced stores.
// sm must be 16B-aligned, 9216 bytes.
// ---------------------------------------------------------------------------
__device__ __forceinline__ void transpose64_body(
    const float* __restrict__ src, __bf16* __restrict__ dst, int R, int Cc,
    int bx, int by, int e, int t, char* sm)
{
    __bf16 (*T)[72] = (__bf16(*)[72])sm;
    const int cb = bx * 64;
    const int rb = by * 64;
    const int px = t & 15, py = t >> 4;

    const float* s = src + (size_t)e * R * Cc
                   + (size_t)(rb + py * 4) * Cc + cb + px * 4;
    float4 m[4];
#pragma unroll
    for (int i = 0; i < 4; ++i)
        m[i] = *(const float4*)(s + (size_t)i * Cc);
#pragma unroll
    for (int j = 0; j < 4; ++j) {
        bf16x4 v;
        v[0] = (__bf16)((&m[0].x)[j]);
        v[1] = (__bf16)((&m[1].x)[j]);
        v[2] = (__bf16)((&m[2].x)[j]);
        v[3] = (__bf16)((&m[3].x)[j]);
        *(bf16x4*)&T[px * 4 + j][py * 4] = v;   // T[c][r] = src[r][c]
    }
    __syncthreads();
    const int oc = t >> 2, rc = (t & 3) * 16;
    __bf16* d = dst + (size_t)e * R * Cc + (size_t)(cb + oc) * R + rb + rc;
    *(bf16x8*)d       = *(const bf16x8*)&T[oc][rc];
    *(bf16x8*)(d + 8) = *(const bf16x8*)&T[oc][rc + 8];
}

// ---------------------------------------------------------------------------
// Prolog: w1 transpose + router (w2 transpose moved into the GEMM1 launch).
//   blocks [0,8192): w1 [E][C][H] -> w1t [E][H][C]
//   blocks [8192,10240): router, 4 tokens/block
// ---------------------------------------------------------------------------
__global__ __launch_bounds__(256) void k_prolog(
    const float* __restrict__ w1, const float* __restrict__ x,
    const float* __restrict__ rw, const float* __restrict__ rb,
    __bf16* __restrict__ w1t, float* __restrict__ probs,
    float* __restrict__ gates, int* __restrict__ tidx)
{
    __shared__ char sm[32768];     // transpose: 9216B; router: 32KB
    const int bid = blockIdx.x;
    const int t   = threadIdx.x;

    if (bid < 8192) {              // w1: R=CDIM, Cc=HDIM (64 x 16 x 8)
        const int bx = bid & 63, by = (bid >> 6) & 15, e = bid >> 10;
        transpose64_body(w1, w1t, CDIM, HDIM, bx, by, e, t, sm);
        return;
    }

    // ---- router ----
    float* rws = (float*)sm;
    for (int i = t; i < NE * CDIM / 4; i += 256)
        ((float4*)rws)[i] = ((const float4*)rw)[i];
    __syncthreads();

    const int wave = t >> 6, lane = t & 63;
    const int n = (bid - 8192) * 4 + wave;
    const float* xr = x + (size_t)n * CDIM;

    float acc[NE];
#pragma unroll
    for (int e = 0; e < NE; ++e) acc[e] = 0.f;
    for (int j = 0; j < CDIM / 64; ++j) {
        const float xv = xr[j * 64 + lane];
#pragma unroll
        for (int e = 0; e < NE; ++e) acc[e] += xv * rws[e * CDIM + j * 64 + lane];
    }
#pragma unroll
    for (int off = 32; off > 0; off >>= 1) {
#pragma unroll
        for (int e = 0; e < NE; ++e) acc[e] += __shfl_down(acc[e], off);
    }
    if (lane == 0) {
        float mx = -1e30f;
#pragma unroll
        for (int e = 0; e < NE; ++e) { acc[e] += rb[e]; mx = fmaxf(mx, acc[e]); }
        float p[NE], s = 0.f;
#pragma unroll
        for (int e = 0; e < NE; ++e) { p[e] = expf(acc[e] - mx); s += p[e]; }
        const float inv = 1.f / s;
#pragma unroll
        for (int e = 0; e < NE; ++e) { p[e] *= inv; probs[(size_t)n * NE + e] = p[e]; }
        int   i1 = 0;  float v1 = p[0];
        int   i2 = -1; float v2 = -1.f;
#pragma unroll
        for (int e = 1; e < NE; ++e) {
            if (p[e] > v1)      { v2 = v1; i2 = i1; v1 = p[e]; i1 = e; }
            else if (p[e] > v2) { v2 = p[e]; i2 = e; }
        }
        const float gs = 1.f / (v1 + v2);
        gates[n * 2 + 0] = v1 * gs;  gates[n * 2 + 1] = v2 * gs;
        tidx[n * 2 + 0]  = i1;       tidx[n * 2 + 1]  = i2;
    }
}

// ---------------------------------------------------------------------------
// Single-block scan — Hillis-Steele log-scan + tree reduce (replay-proven R10).
// ---------------------------------------------------------------------------
__global__ __launch_bounds__(256) void k_scan(
    const int* __restrict__ tidx, const float* __restrict__ probs,
    int* __restrict__ slot, int* __restrict__ tok, float* __restrict__ d_aux)
{
    __shared__ int   lcnt[256][NE];
    __shared__ float ps[256][NE];
    const int t = threadIdx.x;

    for (int i = t; i < NE * CAPE; i += 256) tok[i] = 0;

    int c8[NE];
#pragma unroll
    for (int e = 0; e < NE; ++e) c8[e] = 0;
    const int per  = NSLOT / 256;   // 64
    const int base = t * per;
    for (int s = 0; s < per; ++s) c8[tidx[base + s]]++;
#pragma unroll
    for (int e = 0; e < NE; ++e) lcnt[t][e] = c8[e];

    float f8[NE];
#pragma unroll
    for (int e = 0; e < NE; ++e) f8[e] = 0.f;
    for (int n = t; n < NTOK; n += 256) {
        const float4 a = *(const float4*)(probs + (size_t)n * NE);
        const float4 b = *(const float4*)(probs + (size_t)n * NE + 4);
        f8[0] += a.x; f8[1] += a.y; f8[2] += a.z; f8[3] += a.w;
        f8[4] += b.x; f8[5] += b.y; f8[6] += b.z; f8[7] += b.w;
    }
#pragma unroll
    for (int e = 0; e < NE; ++e) ps[t][e] = f8[e];

    __syncthreads();

    int run[NE];
#pragma unroll
    for (int e = 0; e < NE; ++e) run[e] = c8[e];
    for (int d = 1; d < 256; d <<= 1) {
        int add[NE];
#pragma unroll
        for (int e = 0; e < NE; ++e) add[e] = (t >= d) ? lcnt[t - d][e] : 0;
        __syncthreads();
#pragma unroll
        for (int e = 0; e < NE; ++e) { run[e] += add[e]; lcnt[t][e] = run[e]; }
        __syncthreads();
    }
    int pre[NE], tot[NE];
#pragma unroll
    for (int e = 0; e < NE; ++e) {
        pre[e] = run[e] - c8[e];
        tot[e] = lcnt[255][e];
    }

    for (int d = 128; d >= 1; d >>= 1) {
        if (t < d) {
#pragma unroll
            for (int e = 0; e < NE; ++e) ps[t][e] += ps[t + d][e];
        }
        __syncthreads();
    }

    for (int s = 0; s < per; ++s) {
        const int sg = base + s;
        const int e  = tidx[sg];
        const int p  = pre[e]++;
        if (p < CAPE) { slot[sg] = e * CAPE + p; tok[e * CAPE + p] = sg >> 1; }
        else          { slot[sg] = -1; }
    }
    if (t == 0) {
        float isum = 0.f, lsum = 0.f, ld[NE];
#pragma unroll
        for (int e = 0; e < NE; ++e) isum += ps[0][e];
#pragma unroll
        for (int e = 0; e < NE; ++e) { ld[e] = fminf((float)tot[e], (float)CAPE); lsum += ld[e]; }
        float aux = 0.f;
#pragma unroll
        for (int e = 0; e < NE; ++e) aux += (ps[0][e] / isum) * (ld[e] / lsum);
        *d_aux = aux * (float)(NE * NE);
    }
}

// ---------------------------------------------------------------------------
// Gather tokens into dense per-expert buffers, fp32 -> bf16.
// ---------------------------------------------------------------------------
__global__ __launch_bounds__(256) void k_gather(
    const float* __restrict__ x, const int* __restrict__ tok,
    __bf16* __restrict__ inp)
{
    const int row = blockIdx.x;
    const int t   = threadIdx.x;
    const int tk  = tok[row];
    const float4 v = ((const float4*)(x + (size_t)tk * CDIM))[t];
    bf16x4 o;
    o[0] = (__bf16)v.x; o[1] = (__bf16)v.y; o[2] = (__bf16)v.z; o[3] = (__bf16)v.w;
    *(bf16x4*)(inp + (size_t)row * CDIM + t * 4) = o;
}

// ---------------------------------------------------------------------------
// GEMM core macros — m201 8-phase structure (replay-proven R10/R12).
// ---------------------------------------------------------------------------
#define MFMA_BF16 __builtin_amdgcn_mfma_f32_16x16x32_bf16
#define DSR_I(dst, addr, IMM) \
    asm volatile("ds_read_b128 %0, %1 offset:" #IMM : "=v"(dst) : "v"(addr))
#define DSR(dst, addr, IMM) DSR_I(dst, addr, IMM)
#define WVM4() asm volatile("s_waitcnt vmcnt(4)" ::: "memory")
#define SB0()  __builtin_amdgcn_sched_barrier(0)

#define PH(RDB, OA0, OA1, MB, VA0, VA1, VB0, VB1, STG, VMW)                   \
    {                                                                         \
        if (RDB) {                                                            \
            DSR(fb[0][0], VB0, 0);    DSR(fb[0][1], VB1, 0);                  \
            DSR(fb[1][0], VB0, 2048); DSR(fb[1][1], VB1, 2048);               \
            DSR(fb[2][0], VB0, 4096); DSR(fb[2][1], VB1, 4096);               \
            DSR(fb[3][0], VB0, 6144); DSR(fb[3][1], VB1, 6144);               \
        }                                                                     \
        DSR(fa[0][0], VA0, OA0); DSR(fa[0][1], VA1, OA0);                     \
        DSR(fa[1][0], VA0, OA1); DSR(fa[1][1], VA1, OA1);                     \
        STG;                                                                  \
        if (RDB) { asm volatile("s_waitcnt lgkmcnt(8)" ::: "memory"); }       \
        __builtin_amdgcn_s_barrier();                                         \
        asm volatile("s_waitcnt lgkmcnt(0)" ::: "memory");                    \
        SB0();                                                                \
        __builtin_amdgcn_s_setprio(1);                                        \
        _Pragma("unroll")                                                     \
        for (int n = 0; n < 4; ++n) {                                         \
            acc[MB][n]   = MFMA_BF16(fb[n][0], fa[0][0], acc[MB][n], 0,0,0);  \
            acc[MB][n]   = MFMA_BF16(fb[n][1], fa[0][1], acc[MB][n], 0,0,0);  \
            acc[MB+1][n] = MFMA_BF16(fb[n][0], fa[1][0], acc[MB+1][n],0,0,0); \
            acc[MB+1][n] = MFMA_BF16(fb[n][1], fa[1][1], acc[MB+1][n],0,0,0); \
        }                                                                     \
        __builtin_amdgcn_s_setprio(0);                                        \
        VMW;                                                                  \
        __builtin_amdgcn_s_barrier();                                        \
        SB0();                                                                \
    }

// GEMM body as a macro so the fused kernel and k_gemm8 share code exactly.
// Requires: lds, Aall, Ball, biasAll, Call, Ktot, Ntot, NBN, mtPerE, sid, GELU_F
#define GEMM_BODY(GELU_F)                                                     \
    const int NK  = Ktot >> 6;                                                \
    const int NI  = NK >> 1;                                                  \
    const int bm  = sid / NBN, bn = sid % NBN;                                \
    const int e   = bm / mtPerE;                                              \
    const size_t row0 = (size_t)bm * 256;                                     \
    const int    col0 = bn * 256;                                             \
    const int tid = threadIdx.x;                                              \
    const int w   = tid >> 6, l = tid & 63;                                   \
    const int wr  = w >> 2, wc = w & 3;                                       \
    const int lr  = l & 15, hi = l >> 4;                                      \
    const int srow = tid >> 3;                                                \
    const int kf   = ((tid & 7) ^ (srow & 7)) << 3;                           \
    const __bf16* pA = Aall + (row0 + srow) * (size_t)Ktot + kf;              \
    const __bf16* pB = Ball + ((size_t)e * Ntot + col0 + srow) * (size_t)Ktot + kf; \
    const unsigned L0 = (unsigned)(size_t)(LAS char*)lds;                     \
    const unsigned sA00 = L0 +          w * 1024;                             \
    const unsigned sA01 = sA00 + 16384;                                       \
    const unsigned sA10 = sA00 + 32768;                                       \
    const unsigned sA11 = sA00 + 49152;                                       \
    const unsigned sB00 = sA00 + 65536;                                       \
    const unsigned sB01 = sB00 + 16384;                                       \
    const unsigned sB10 = sB00 + 32768;                                       \
    const unsigned sB11 = sB00 + 49152;                                       \
    auto SH_A = [&](unsigned dbase, int half, int kt) {                       \
        const __bf16* g = pA + (size_t)(half * 128) * Ktot + (size_t)kt * 64; \
        _Pragma("unroll")                                                     \
        for (int gg = 0; gg < 2; ++gg)                                        \
            __builtin_amdgcn_global_load_lds(                                 \
                (const GAS void*)(g + (size_t)gg * 64 * Ktot),                \
                (LAS void*)(size_t)(dbase + gg * 8192), 16, 0, 0);            \
    };                                                                        \
    auto SH_B = [&](unsigned dbase, int half, int kt) {                       \
        const __bf16* g = pB + (size_t)(half * 128) * Ktot + (size_t)kt * 64; \
        _Pragma("unroll")                                                     \
        for (int gg = 0; gg < 2; ++gg)                                        \
            __builtin_amdgcn_global_load_lds(                                 \
                (const GAS void*)(g + (size_t)gg * 64 * Ktot),                \
                (LAS void*)(size_t)(dbase + gg * 8192), 16, 0, 0);            \
    };                                                                        \
    const unsigned swz = (l & 7) << 4;                                        \
    const unsigned kb0 = ((unsigned)(hi << 4)) ^ swz;                         \
    const unsigned kb1 = ((unsigned)(64 + (hi << 4))) ^ swz;                  \
    const unsigned vA00 = L0 + (unsigned)(wr * 16384 + lr * 128) + kb0;       \
    const unsigned vA01 = L0 + (unsigned)(wr * 16384 + lr * 128) + kb1;       \
    const unsigned vA10 = vA00 + 32768, vA11 = vA01 + 32768;                  \
    const unsigned vBb  = L0 + 65536                                          \
        + (unsigned)((wc >> 1) * 16384 + ((wc & 1) * 64 + lr) * 128);         \
    const unsigned vB00 = vBb + kb0, vB01 = vBb + kb1;                        \
    const unsigned vB10 = vB00 + 32768, vB11 = vB01 + 32768;                  \
    SH_B(sB00, 0, 0); SH_B(sB01, 1, 0);                                       \
    SH_A(sA00, 0, 0); SH_A(sA01, 1, 0);                                       \
    SH_B(sB10, 0, 1); SH_B(sB11, 1, 1);                                       \
    WVM4();                                                                   \
    __builtin_amdgcn_s_barrier();                                             \
    SB0();                                                                    \
    f32x4 acc[8][4] = {};                                                     \
    bf16x8 fa[2][2], fb[4][2];                                                \
    for (int i = 0; i < NI; ++i) {                                            \
        const int t1 = 2 * i + 1;                                             \
        const int t2 = (2 * i + 2 < NK) ? 2 * i + 2 : NK - 1;                 \
        const int t3 = (2 * i + 3 < NK) ? 2 * i + 3 : NK - 1;                 \
        PH(1, 0,     2048,  0, vA00, vA01, vB00, vB01, SH_A(sA10, 0, t1), (void)0) \
        PH(0, 4096,  6144,  2, vA00, vA01, vB00, vB01, SH_A(sA11, 1, t1), (void)0) \
        PH(0, 8192,  10240, 4, vA00, vA01, vB00, vB01, SH_B(sB00, 0, t2), (void)0) \
        PH(0, 12288, 14336, 6, vA00, vA01, vB00, vB01, SH_B(sB01, 1, t2), WVM4())  \
        PH(1, 0,     2048,  0, vA10, vA11, vB10, vB11, SH_A(sA00, 0, t2), (void)0) \
        PH(0, 4096,  6144,  2, vA10, vA11, vB10, vB11, SH_A(sA01, 1, t2), (void)0) \
        PH(0, 8192,  10240, 4, vA10, vA11, vB10, vB11, SH_B(sB10, 0, t3), (void)0) \
        PH(0, 12288, 14336, 6, vA10, vA11, vB10, vB11, SH_B(sB11, 1, t3), WVM4())  \
    }                                                                         \
    asm volatile("s_waitcnt vmcnt(0)" ::: "memory");                          \
    __builtin_amdgcn_s_barrier();                                             \
    SB0();                                                                    \
    const int lrow0 = wr * 128;                                               \
    const int lcol0 = wc * 64;                                                \
    _Pragma("unroll")                                                         \
    for (int n = 0; n < 4; ++n) {                                             \
        float bbv[4] = {0.f, 0.f, 0.f, 0.f};                                  \
        if (GELU_F) {                                                         \
            const float4 b4 = *(const float4*)(biasAll + (size_t)e * Ntot     \
                                               + col0 + lcol0 + n * 16 + hi * 4); \
            bbv[0] = b4.x; bbv[1] = b4.y; bbv[2] = b4.z; bbv[3] = b4.w;       \
        }                                                                     \
        _Pragma("unroll")                                                     \
        for (int m = 0; m < 8; ++m) {                                         \
            const f32x4 v = acc[m][n];                                        \
            bf16x4 o;                                                         \
            _Pragma("unroll")                                                 \
            for (int i = 0; i < 4; ++i) {                                     \
                float t = v[i];                                               \
                if (GELU_F) {                                                 \
                    t += bbv[i];                                              \
                    const float u  = 0.7978845608028654f * (t + 0.044715f * t * t * t); \
                    const float ex = __expf(2.f * u);                         \
                    t = t * (1.f - 1.f / (ex + 1.f));                         \
                }                                                             \
                o[i] = (__bf16)t;                                             \
            }                                                                 \
            *(bf16x4*)(lds + (lrow0 + m * 16 + lr) * 520                      \
                           + (lcol0 + n * 16 + hi * 4) * 2) = o;              \
        }                                                                     \
    }                                                                         \
    __builtin_amdgcn_s_barrier();                                             \
    {                                                                         \
        const int rr0 = tid >> 5;                                             \
        const int cc  = (tid & 31) * 8;                                       \
        _Pragma("unroll")                                                     \
        for (int it = 0; it < 16; ++it) {                                     \
            const int rr = it * 16 + rr0;                                     \
            const bf16x8 v = *(const bf16x8*)(lds + rr * 520 + cc * 2);       \
            *(bf16x8*)(Call + (row0 + rr) * (size_t)Ntot + col0 + cc) = v;    \
        }                                                                     \
    }

// ---------------------------------------------------------------------------
// Fused launch: GEMM1 (blocks [0,640)) + w2 transpose (blocks [640, 640+4096)).
// Transpose blocks dispatch after GEMM blocks and fill the GEMM1 tail /
// idle CUs (GEMM1 = 2.5 rounds at 1 block/CU, HBM at ~19%).
// ---------------------------------------------------------------------------
__global__ __launch_bounds__(512, 2) void k_g1w2t(
    const __bf16* __restrict__ Aall, const __bf16* __restrict__ Ball,
    const float* __restrict__ biasAll, __bf16* __restrict__ Call,
    const float* __restrict__ w2, __bf16* __restrict__ w2t)
{
    __shared__ char lds[133120];

    if (blockIdx.x < G1BLK) {
        // ---- GEMM1: 256^2 8-phase, GELU epilogue ----
        const int Ktot = CDIM, Ntot = HDIM, NBN = HDIM / 256, mtPerE = CAPE / 256;
        const int id  = blockIdx.x;
        const int sid = (id & 7) * (G1BLK >> 3) + (id >> 3);   // bijective XCD swizzle
        GEMM_BODY(true)
        return;
    }

    // ---- w2 transpose: two 64x64 tiles per 512-thread block ----
    const int b2   = blockIdx.x - G1BLK;
    const int sub  = threadIdx.x >> 8;          // 0 or 1
    const int t    = threadIdx.x & 255;
    const int tile = b2 * 2 + sub;              // 0..8191
    const int bx = tile & 15, by = (tile >> 4) & 63, e = tile >> 10;
    transpose64_body(w2, w2t, HDIM, CDIM, bx, by, e, t, lds + sub * 9216);
}

// ---------------------------------------------------------------------------
// GEMM2: standalone (no GELU), same proven body.
// ---------------------------------------------------------------------------
__global__ __launch_bounds__(512, 2) void k_gemm8(
    const __bf16* __restrict__ Aall, const __bf16* __restrict__ Ball,
    const float* __restrict__ biasAll, __bf16* __restrict__ Call,
    int Ktot, int Ntot, int NBN, int mtPerE)
{
    __shared__ char lds[133120];
    const int cpx = gridDim.x >> 3;
    const int id  = blockIdx.x;
    const int sid = (id & 7) * cpx + (id >> 3);
    GEMM_BODY(false)
}

// ---------------------------------------------------------------------------
// Combine: y[n][c] = sum_k gate * (out[slot][c] + b2[e][c]); writes all of y.
// ---------------------------------------------------------------------------
__global__ __launch_bounds__(256) void k_combine(
    const __bf16* __restrict__ outb, const int* __restrict__ slot,
    const float* __restrict__ gates, const int* __restrict__ tidx,
    const float* __restrict__ b2, float* __restrict__ y)
{
    const int n = blockIdx.x;
    const int t = threadIdx.x;
    const int c = t * 4;
    float r0 = 0.f, r1 = 0.f, r2 = 0.f, r3 = 0.f;
#pragma unroll
    for (int k = 0; k < KTOP; ++k) {
        const int s = slot[n * 2 + k];
        if (s < 0) continue;
        const float g = gates[n * 2 + k];
        const int   e = tidx[n * 2 + k];
        const bf16x4 v = *(const bf16x4*)(outb + (size_t)s * CDIM + c);
        const float4 bb = *(const float4*)(b2 + (size_t)e * CDIM + c);
        r0 += g * ((float)v[0] + bb.x);
        r1 += g * ((float)v[1] + bb.y);
        r2 += g * ((float)v[2] + bb.z);
        r3 += g * ((float)v[3] + bb.w);
    }
    float4 o = make_float4(r0, r1, r2, r3);
    *(float4*)(y + (size_t)n * CDIM + c) = o;
}

// ---------------------------------------------------------------------------
extern "C" void kernel_launch(void* const* d_in, const int* in_sizes, int n_in,
                              void* d_out, int out_size, void* d_ws, size_t ws_size,
                              hipStream_t stream)
{
    const float* x  = (const float*)d_in[0];
    const float* rw = (const float*)d_in[1];
    const float* rb = (const float*)d_in[2];
    const float* w1 = (const float*)d_in[3];
    const float* b1 = (const float*)d_in[4];
    const float* w2 = (const float*)d_in[5];
    const float* b2 = (const float*)d_in[6];
    float* y = (float*)d_out;

    char* ws = (char*)d_ws;
    size_t off = 0;
    auto alloc = [&](size_t bytes) -> void* {
        void* p = ws + off;
        off = (off + bytes + 255) & ~(size_t)255;
        return p;
    };
    __bf16* w1t  = (__bf16*)alloc((size_t)NE * CDIM * HDIM * 2);   // [E][H][C]
    __bf16* w2t  = (__bf16*)alloc((size_t)NE * CDIM * HDIM * 2);   // [E][C][H]
    __bf16* inp  = (__bf16*)alloc((size_t)NE * CAPE * CDIM * 2);   // [E*cap][C]
    __bf16* hbuf = (__bf16*)alloc((size_t)NE * CAPE * HDIM * 2);   // [E*cap][H]
    __bf16* outb = (__bf16*)alloc((size_t)NE * CAPE * CDIM * 2);   // [E*cap][C]
    float*  probs = (float*)alloc((size_t)NTOK * NE * 4);
    float*  gates = (float*)alloc((size_t)NTOK * 2 * 4);
    int*    tidx  = (int*)alloc((size_t)NTOK * 2 * 4);
    int*    slot  = (int*)alloc((size_t)NTOK * 2 * 4);
    int*    tok   = (int*)alloc((size_t)NE * CAPE * 4);

    // 1. prolog: w1 transpose + router
    k_prolog<<<8192 + NTOK / 4, 256, 0, stream>>>(
        w1, x, rw, rb, w1t, probs, gates, tidx);

    // 2. dispatch scan + aux loss (single block, log-scan)
    k_scan<<<1, 256, 0, stream>>>(tidx, probs, slot, tok, y + (size_t)NTOK * CDIM);

    // 3. gather expert inputs (bf16)
    k_gather<<<NE * CAPE, 256, 0, stream>>>(x, tok, inp);

    // 4. fused GEMM1 + w2 transpose (transpose fills GEMM1's idle tail CUs)
    k_g1w2t<<<G1BLK + 4096, 512, 0, stream>>>(inp, w1t, b1, hbuf, w2, w2t);

    // 5. GEMM2
    k_gemm8<<<dim3((NE * CAPE / 256) * (CDIM / 256)), 512, 0, stream>>>(
        hbuf, w2t, nullptr, outb, HDIM, CDIM, CDIM / 256, CAPE / 256);

    // 6. combine back to tokens (+aux already written by scan)
    k_combine<<<NTOK, 256, 0, stream>>>(outb, slot, gates, tidx, b2, y);
}

// Round 14
// 353.510 us; speedup vs baseline: 1.6519x; 1.0034x over previous
//
#include <hip/hip_runtime.h>
#include <hip/hip_bf16.h>
#include <math.h>

#define NE    8
#define KTOP  2
#define CDIM  1024
#define HDIM  4096
#define NTOK  8192
#define CAPE  1280
#define NSLOT (NTOK * KTOP)
#define G1BLK 640            // GEMM1 sub-grid in the fused launch (640 % 8 == 0)

typedef __bf16 bf16x8 __attribute__((ext_vector_type(8)));
typedef __bf16 bf16x4 __attribute__((ext_vector_type(4)));
typedef float  f32x4  __attribute__((ext_vector_type(4)));

#define GAS __attribute__((address_space(1)))
#define LAS __attribute__((address_space(3)))

// ---------------------------------------------------------------------------
// Transpose body: 64x64 tile, 4x4 register blocklet, bf16x8 coalesced stores.
// ---------------------------------------------------------------------------
__device__ __forceinline__ void transpose64_body(
    const float* __restrict__ src, __bf16* __restrict__ dst, int R, int Cc,
    int bx, int by, int e, int t, char* sm)
{
    __bf16 (*T)[72] = (__bf16(*)[72])sm;
    const int cb = bx * 64;
    const int rb = by * 64;
    const int px = t & 15, py = t >> 4;

    const float* s = src + (size_t)e * R * Cc
                   + (size_t)(rb + py * 4) * Cc + cb + px * 4;
    float4 m[4];
#pragma unroll
    for (int i = 0; i < 4; ++i)
        m[i] = *(const float4*)(s + (size_t)i * Cc);
#pragma unroll
    for (int j = 0; j < 4; ++j) {
        bf16x4 v;
        v[0] = (__bf16)((&m[0].x)[j]);
        v[1] = (__bf16)((&m[1].x)[j]);
        v[2] = (__bf16)((&m[2].x)[j]);
        v[3] = (__bf16)((&m[3].x)[j]);
        *(bf16x4*)&T[px * 4 + j][py * 4] = v;   // T[c][r] = src[r][c]
    }
    __syncthreads();
    const int oc = t >> 2, rc = (t & 3) * 16;
    __bf16* d = dst + (size_t)e * R * Cc + (size_t)(cb + oc) * R + rb + rc;
    *(bf16x8*)d       = *(const bf16x8*)&T[oc][rc];
    *(bf16x8*)(d + 8) = *(const bf16x8*)&T[oc][rc + 8];
}

// ---------------------------------------------------------------------------
// Prolog: w1 transpose + router.
// ---------------------------------------------------------------------------
__global__ __launch_bounds__(256) void k_prolog(
    const float* __restrict__ w1, const float* __restrict__ x,
    const float* __restrict__ rw, const float* __restrict__ rb,
    __bf16* __restrict__ w1t, float* __restrict__ probs,
    float* __restrict__ gates, int* __restrict__ tidx)
{
    __shared__ char sm[32768];
    const int bid = blockIdx.x;
    const int t   = threadIdx.x;

    if (bid < 8192) {              // w1: R=CDIM, Cc=HDIM
        const int bx = bid & 63, by = (bid >> 6) & 15, e = bid >> 10;
        transpose64_body(w1, w1t, CDIM, HDIM, bx, by, e, t, sm);
        return;
    }

    // ---- router ----
    float* rws = (float*)sm;
    for (int i = t; i < NE * CDIM / 4; i += 256)
        ((float4*)rws)[i] = ((const float4*)rw)[i];
    __syncthreads();

    const int wave = t >> 6, lane = t & 63;
    const int n = (bid - 8192) * 4 + wave;
    const float* xr = x + (size_t)n * CDIM;

    float acc[NE];
#pragma unroll
    for (int e = 0; e < NE; ++e) acc[e] = 0.f;
    for (int j = 0; j < CDIM / 64; ++j) {
        const float xv = xr[j * 64 + lane];
#pragma unroll
        for (int e = 0; e < NE; ++e) acc[e] += xv * rws[e * CDIM + j * 64 + lane];
    }
#pragma unroll
    for (int off = 32; off > 0; off >>= 1) {
#pragma unroll
        for (int e = 0; e < NE; ++e) acc[e] += __shfl_down(acc[e], off);
    }
    if (lane == 0) {
        float mx = -1e30f;
#pragma unroll
        for (int e = 0; e < NE; ++e) { acc[e] += rb[e]; mx = fmaxf(mx, acc[e]); }
        float p[NE], s = 0.f;
#pragma unroll
        for (int e = 0; e < NE; ++e) { p[e] = expf(acc[e] - mx); s += p[e]; }
        const float inv = 1.f / s;
#pragma unroll
        for (int e = 0; e < NE; ++e) { p[e] *= inv; probs[(size_t)n * NE + e] = p[e]; }
        int   i1 = 0;  float v1 = p[0];
        int   i2 = -1; float v2 = -1.f;
#pragma unroll
        for (int e = 1; e < NE; ++e) {
            if (p[e] > v1)      { v2 = v1; i2 = i1; v1 = p[e]; i1 = e; }
            else if (p[e] > v2) { v2 = p[e]; i2 = e; }
        }
        const float gs = 1.f / (v1 + v2);
        gates[n * 2 + 0] = v1 * gs;  gates[n * 2 + 1] = v2 * gs;
        tidx[n * 2 + 0]  = i1;       tidx[n * 2 + 1]  = i2;
    }
}

// ---------------------------------------------------------------------------
// Single-block scan — Hillis-Steele log-scan + tree reduce (replay-proven).
// ---------------------------------------------------------------------------
__global__ __launch_bounds__(256) void k_scan(
    const int* __restrict__ tidx, const float* __restrict__ probs,
    int* __restrict__ slot, int* __restrict__ tok, float* __restrict__ d_aux)
{
    __shared__ int   lcnt[256][NE];
    __shared__ float ps[256][NE];
    const int t = threadIdx.x;

    for (int i = t; i < NE * CAPE; i += 256) tok[i] = 0;

    int c8[NE];
#pragma unroll
    for (int e = 0; e < NE; ++e) c8[e] = 0;
    const int per  = NSLOT / 256;   // 64
    const int base = t * per;
    for (int s = 0; s < per; ++s) c8[tidx[base + s]]++;
#pragma unroll
    for (int e = 0; e < NE; ++e) lcnt[t][e] = c8[e];

    float f8[NE];
#pragma unroll
    for (int e = 0; e < NE; ++e) f8[e] = 0.f;
    for (int n = t; n < NTOK; n += 256) {
        const float4 a = *(const float4*)(probs + (size_t)n * NE);
        const float4 b = *(const float4*)(probs + (size_t)n * NE + 4);
        f8[0] += a.x; f8[1] += a.y; f8[2] += a.z; f8[3] += a.w;
        f8[4] += b.x; f8[5] += b.y; f8[6] += b.z; f8[7] += b.w;
    }
#pragma unroll
    for (int e = 0; e < NE; ++e) ps[t][e] = f8[e];

    __syncthreads();

    int run[NE];
#pragma unroll
    for (int e = 0; e < NE; ++e) run[e] = c8[e];
    for (int d = 1; d < 256; d <<= 1) {
        int add[NE];
#pragma unroll
        for (int e = 0; e < NE; ++e) add[e] = (t >= d) ? lcnt[t - d][e] : 0;
        __syncthreads();
#pragma unroll
        for (int e = 0; e < NE; ++e) { run[e] += add[e]; lcnt[t][e] = run[e]; }
        __syncthreads();
    }
    int pre[NE], tot[NE];
#pragma unroll
    for (int e = 0; e < NE; ++e) {
        pre[e] = run[e] - c8[e];
        tot[e] = lcnt[255][e];
    }

    for (int d = 128; d >= 1; d >>= 1) {
        if (t < d) {
#pragma unroll
            for (int e = 0; e < NE; ++e) ps[t][e] += ps[t + d][e];
        }
        __syncthreads();
    }

    for (int s = 0; s < per; ++s) {
        const int sg = base + s;
        const int e  = tidx[sg];
        const int p  = pre[e]++;
        if (p < CAPE) { slot[sg] = e * CAPE + p; tok[e * CAPE + p] = sg >> 1; }
        else          { slot[sg] = -1; }
    }
    if (t == 0) {
        float isum = 0.f, lsum = 0.f, ld[NE];
#pragma unroll
        for (int e = 0; e < NE; ++e) isum += ps[0][e];
#pragma unroll
        for (int e = 0; e < NE; ++e) { ld[e] = fminf((float)tot[e], (float)CAPE); lsum += ld[e]; }
        float aux = 0.f;
#pragma unroll
        for (int e = 0; e < NE; ++e) aux += (ps[0][e] / isum) * (ld[e] / lsum);
        *d_aux = aux * (float)(NE * NE);
    }
}

// ---------------------------------------------------------------------------
// Gather tokens into dense per-expert buffers, fp32 -> bf16.
// ---------------------------------------------------------------------------
__global__ __launch_bounds__(256) void k_gather(
    const float* __restrict__ x, const int* __restrict__ tok,
    __bf16* __restrict__ inp)
{
    const int row = blockIdx.x;
    const int t   = threadIdx.x;
    const int tk  = tok[row];
    const float4 v = ((const float4*)(x + (size_t)tk * CDIM))[t];
    bf16x4 o;
    o[0] = (__bf16)v.x; o[1] = (__bf16)v.y; o[2] = (__bf16)v.z; o[3] = (__bf16)v.w;
    *(bf16x4*)(inp + (size_t)row * CDIM + t * 4) = o;
}

// ---------------------------------------------------------------------------
// 256x256 8-wave GEMM — quadrant-phase variant: 4 phases/K-tile, ONE barrier
// per phase (closing only; drift <1 phase keeps the R6 ring race-free:
// P3's B-restage is ordered by BAR_P2 after all fb reads completed at P1).
// Reads per phase: 12/4/8/0; A/B fragments persist in regs across phases so
// P4 enters MFMA with zero outstanding LDS reads. vmcnt(4) gates unchanged.
// ---------------------------------------------------------------------------
#define MFMA_BF16 __builtin_amdgcn_mfma_f32_16x16x32_bf16
#define DSR_I(dst, addr, IMM) \
    asm volatile("ds_read_b128 %0, %1 offset:" #IMM : "=v"(dst) : "v"(addr))
#define DSR(dst, addr, IMM) DSR_I(dst, addr, IMM)
#define WVM4() asm volatile("s_waitcnt vmcnt(4)" ::: "memory")
#define WLG0() asm volatile("s_waitcnt lgkmcnt(0)" ::: "memory")
#define SB0()  __builtin_amdgcn_sched_barrier(0)

// Quadrant MFMA: m in [0,4) of current fa, n in [NB,NB+2), both k-halves.
#define QMFMA(MROW, NB)                                                      \
    __builtin_amdgcn_s_setprio(1);                                           \
    _Pragma("unroll")                                                        \
    for (int n = 0; n < 2; ++n) {                                            \
        _Pragma("unroll")                                                    \
        for (int m = 0; m < 4; ++m) {                                        \
            acc[(MROW) + m][(NB) + n] = MFMA_BF16(fb[(NB) + n][0], fa[m][0], \
                acc[(MROW) + m][(NB) + n], 0, 0, 0);                         \
            acc[(MROW) + m][(NB) + n] = MFMA_BF16(fb[(NB) + n][1], fa[m][1], \
                acc[(MROW) + m][(NB) + n], 0, 0, 0);                         \
        }                                                                    \
    }                                                                        \
    __builtin_amdgcn_s_setprio(0);

// One K-tile = 4 quadrant phases. VA0/VA1,VB0/VB1: swizzled bases (kh0/kh1).
#define KTILE(VA0, VA1, VB0, VB1, STG1, STG2, STG3, STG4)                    \
    {                                                                        \
        /* P1: fa m0-3 (8) + fb n0-1 (4) */                                  \
        DSR(fa[0][0], VA0, 0);    DSR(fa[0][1], VA1, 0);                     \
        DSR(fa[1][0], VA0, 2048); DSR(fa[1][1], VA1, 2048);                  \
        DSR(fa[2][0], VA0, 4096); DSR(fa[2][1], VA1, 4096);                  \
        DSR(fa[3][0], VA0, 6144); DSR(fa[3][1], VA1, 6144);                  \
        DSR(fb[0][0], VB0, 0);    DSR(fb[0][1], VB1, 0);                     \
        DSR(fb[1][0], VB0, 2048); DSR(fb[1][1], VB1, 2048);                  \
        STG1;                                                                \
        WLG0(); SB0();                                                       \
        QMFMA(0, 0)                                                          \
        __builtin_amdgcn_s_barrier(); SB0();                                 \
        /* P2: fb n2-3 (4) */                                                \
        DSR(fb[2][0], VB0, 4096); DSR(fb[2][1], VB1, 4096);                  \
        DSR(fb[3][0], VB0, 6144); DSR(fb[3][1], VB1, 6144);                  \
        STG2;                                                                \
        WLG0(); SB0();                                                       \
        QMFMA(0, 2)                                                          \
        __builtin_amdgcn_s_barrier(); SB0();                                 \
        /* P3: fa m4-7 (8) */                                                \
        DSR(fa[0][0], VA0, 8192);  DSR(fa[0][1], VA1, 8192);                 \
        DSR(fa[1][0], VA0, 10240); DSR(fa[1][1], VA1, 10240);                \
        DSR(fa[2][0], VA0, 12288); DSR(fa[2][1], VA1, 12288);                \
        DSR(fa[3][0], VA0, 14336); DSR(fa[3][1], VA1, 14336);                \
        STG3;                                                                \
        WLG0(); SB0();                                                       \
        QMFMA(4, 0)                                                          \
        __builtin_amdgcn_s_barrier(); SB0();                                 \
        /* P4: no reads */                                                   \
        STG4;                                                                \
        QMFMA(4, 2)                                                          \
        WVM4();                                                              \
        __builtin_amdgcn_s_barrier(); SB0();                                 \
    }

// Shared GEMM body. Requires: lds, Aall, Ball, biasAll, Call, Ktot, Ntot,
// NBN, mtPerE, sid, GELU_F.
#define GEMM_BODY(GELU_F)                                                     \
    const int NK  = Ktot >> 6;                                                \
    const int NI  = NK >> 1;                                                  \
    const int bm  = sid / NBN, bn = sid % NBN;                                \
    const int e   = bm / mtPerE;                                              \
    const size_t row0 = (size_t)bm * 256;                                     \
    const int    col0 = bn * 256;                                             \
    const int tid = threadIdx.x;                                              \
    const int w   = tid >> 6, l = tid & 63;                                   \
    const int wr  = w >> 2, wc = w & 3;                                       \
    const int lr  = l & 15, hi = l >> 4;                                      \
    const int srow = tid >> 3;                                                \
    const int kf   = ((tid & 7) ^ (srow & 7)) << 3;                           \
    const __bf16* pA = Aall + (row0 + srow) * (size_t)Ktot + kf;              \
    const __bf16* pB = Ball + ((size_t)e * Ntot + col0 + srow) * (size_t)Ktot + kf; \
    const unsigned L0 = (unsigned)(size_t)(LAS char*)lds;                     \
    const unsigned sA00 = L0 +          w * 1024;                             \
    const unsigned sA01 = sA00 + 16384;                                       \
    const unsigned sA10 = sA00 + 32768;                                       \
    const unsigned sA11 = sA00 + 49152;                                       \
    const unsigned sB00 = sA00 + 65536;                                       \
    const unsigned sB01 = sB00 + 16384;                                       \
    const unsigned sB10 = sB00 + 32768;                                       \
    const unsigned sB11 = sB00 + 49152;                                       \
    auto SH_A = [&](unsigned dbase, int half, int kt) {                       \
        const __bf16* g = pA + (size_t)(half * 128) * Ktot + (size_t)kt * 64; \
        _Pragma("unroll")                                                     \
        for (int gg = 0; gg < 2; ++gg)                                        \
            __builtin_amdgcn_global_load_lds(                                 \
                (const GAS void*)(g + (size_t)gg * 64 * Ktot),                \
                (LAS void*)(size_t)(dbase + gg * 8192), 16, 0, 0);            \
    };                                                                        \
    auto SH_B = [&](unsigned dbase, int half, int kt) {                       \
        const __bf16* g = pB + (size_t)(half * 128) * Ktot + (size_t)kt * 64; \
        _Pragma("unroll")                                                     \
        for (int gg = 0; gg < 2; ++gg)                                        \
            __builtin_amdgcn_global_load_lds(                                 \
                (const GAS void*)(g + (size_t)gg * 64 * Ktot),                \
                (LAS void*)(size_t)(dbase + gg * 8192), 16, 0, 0);            \
    };                                                                        \
    const unsigned swz = (l & 7) << 4;                                        \
    const unsigned kb0 = ((unsigned)(hi << 4)) ^ swz;                         \
    const unsigned kb1 = ((unsigned)(64 + (hi << 4))) ^ swz;                  \
    const unsigned vA00 = L0 + (unsigned)(wr * 16384 + lr * 128) + kb0;       \
    const unsigned vA01 = L0 + (unsigned)(wr * 16384 + lr * 128) + kb1;       \
    const unsigned vA10 = vA00 + 32768, vA11 = vA01 + 32768;                  \
    const unsigned vBb  = L0 + 65536                                          \
        + (unsigned)((wc >> 1) * 16384 + ((wc & 1) * 64 + lr) * 128);         \
    const unsigned vB00 = vBb + kb0, vB01 = vBb + kb1;                        \
    const unsigned vB10 = vB00 + 32768, vB11 = vB01 + 32768;                  \
    SH_B(sB00, 0, 0); SH_B(sB01, 1, 0);                                       \
    SH_A(sA00, 0, 0); SH_A(sA01, 1, 0);                                       \
    SH_B(sB10, 0, 1); SH_B(sB11, 1, 1);                                       \
    WVM4();                                                                   \
    __builtin_amdgcn_s_barrier();                                             \
    SB0();                                                                    \
    f32x4 acc[8][4] = {};                                                     \
    bf16x8 fa[4][2], fb[4][2];                                                \
    for (int i = 0; i < NI; ++i) {                                            \
        const int t1 = 2 * i + 1;                                             \
        const int t2 = (2 * i + 2 < NK) ? 2 * i + 2 : NK - 1;                 \
        const int t3 = (2 * i + 3 < NK) ? 2 * i + 3 : NK - 1;                 \
        KTILE(vA00, vA01, vB00, vB01,                                         \
              SH_A(sA10, 0, t1), SH_A(sA11, 1, t1),                           \
              SH_B(sB00, 0, t2), SH_B(sB01, 1, t2))                           \
        KTILE(vA10, vA11, vB10, vB11,                                         \
              SH_A(sA00, 0, t2), SH_A(sA01, 1, t2),                           \
              SH_B(sB10, 0, t3), SH_B(sB11, 1, t3))                           \
    }                                                                         \
    asm volatile("s_waitcnt vmcnt(0)" ::: "memory");                          \
    __builtin_amdgcn_s_barrier();                                             \
    SB0();                                                                    \
    const int lrow0 = wr * 128;                                               \
    const int lcol0 = wc * 64;                                                \
    _Pragma("unroll")                                                         \
    for (int n = 0; n < 4; ++n) {                                             \
        float bbv[4] = {0.f, 0.f, 0.f, 0.f};                                  \
        if (GELU_F) {                                                         \
            const float4 b4 = *(const float4*)(biasAll + (size_t)e * Ntot     \
                                               + col0 + lcol0 + n * 16 + hi * 4); \
            bbv[0] = b4.x; bbv[1] = b4.y; bbv[2] = b4.z; bbv[3] = b4.w;       \
        }                                                                     \
        _Pragma("unroll")                                                     \
        for (int m = 0; m < 8; ++m) {                                         \
            const f32x4 v = acc[m][n];                                        \
            bf16x4 o;                                                         \
            _Pragma("unroll")                                                 \
            for (int i = 0; i < 4; ++i) {                                     \
                float t = v[i];                                               \
                if (GELU_F) {                                                 \
                    t += bbv[i];                                              \
                    const float u  = 0.7978845608028654f * (t + 0.044715f * t * t * t); \
                    const float ex = __expf(2.f * u);                         \
                    t = t * (1.f - 1.f / (ex + 1.f));                         \
                }                                                             \
                o[i] = (__bf16)t;                                             \
            }                                                                 \
            *(bf16x4*)(lds + (lrow0 + m * 16 + lr) * 520                      \
                           + (lcol0 + n * 16 + hi * 4) * 2) = o;              \
        }                                                                     \
    }                                                                         \
    __builtin_amdgcn_s_barrier();                                             \
    {                                                                         \
        const int rr0 = tid >> 5;                                             \
        const int cc  = (tid & 31) * 8;                                       \
        _Pragma("unroll")                                                     \
        for (int it = 0; it < 16; ++it) {                                     \
            const int rr = it * 16 + rr0;                                     \
            const bf16x8 v = *(const bf16x8*)(lds + rr * 520 + cc * 2);       \
            *(bf16x8*)(Call + (row0 + rr) * (size_t)Ntot + col0 + cc) = v;    \
        }                                                                     \
    }

// ---------------------------------------------------------------------------
// Fused launch: GEMM1 (blocks [0,640)) + w2 transpose (blocks [640, 640+4096)).
// ---------------------------------------------------------------------------
__global__ __launch_bounds__(512, 2) void k_g1w2t(
    const __bf16* __restrict__ Aall, const __bf16* __restrict__ Ball,
    const float* __restrict__ biasAll, __bf16* __restrict__ Call,
    const float* __restrict__ w2, __bf16* __restrict__ w2t)
{
    __shared__ char lds[133120];

    if (blockIdx.x < G1BLK) {
        const int Ktot = CDIM, Ntot = HDIM, NBN = HDIM / 256, mtPerE = CAPE / 256;
        const int id  = blockIdx.x;
        const int sid = (id & 7) * (G1BLK >> 3) + (id >> 3);   // bijective XCD swizzle
        GEMM_BODY(true)
        return;
    }

    // ---- w2 transpose: two 64x64 tiles per 512-thread block ----
    const int b2   = blockIdx.x - G1BLK;
    const int sub  = threadIdx.x >> 8;          // 0 or 1
    const int t    = threadIdx.x & 255;
    const int tile = b2 * 2 + sub;              // 0..8191
    const int bx = tile & 15, by = (tile >> 4) & 63, e = tile >> 10;
    transpose64_body(w2, w2t, HDIM, CDIM, bx, by, e, t, lds + sub * 9216);
}

// ---------------------------------------------------------------------------
// GEMM2: standalone (no GELU).
// ---------------------------------------------------------------------------
__global__ __launch_bounds__(512, 2) void k_gemm8(
    const __bf16* __restrict__ Aall, const __bf16* __restrict__ Ball,
    const float* __restrict__ biasAll, __bf16* __restrict__ Call,
    int Ktot, int Ntot, int NBN, int mtPerE)
{
    __shared__ char lds[133120];
    const int cpx = gridDim.x >> 3;
    const int id  = blockIdx.x;
    const int sid = (id & 7) * cpx + (id >> 3);
    GEMM_BODY(false)
}

// ---------------------------------------------------------------------------
// Combine: y[n][c] = sum_k gate * (out[slot][c] + b2[e][c]); writes all of y.
// ---------------------------------------------------------------------------
__global__ __launch_bounds__(256) void k_combine(
    const __bf16* __restrict__ outb, const int* __restrict__ slot,
    const float* __restrict__ gates, const int* __restrict__ tidx,
    const float* __restrict__ b2, float* __restrict__ y)
{
    const int n = blockIdx.x;
    const int t = threadIdx.x;
    const int c = t * 4;
    float r0 = 0.f, r1 = 0.f, r2 = 0.f, r3 = 0.f;
#pragma unroll
    for (int k = 0; k < KTOP; ++k) {
        const int s = slot[n * 2 + k];
        if (s < 0) continue;
        const float g = gates[n * 2 + k];
        const int   e = tidx[n * 2 + k];
        const bf16x4 v = *(const bf16x4*)(outb + (size_t)s * CDIM + c);
        const float4 bb = *(const float4*)(b2 + (size_t)e * CDIM + c);
        r0 += g * ((float)v[0] + bb.x);
        r1 += g * ((float)v[1] + bb.y);
        r2 += g * ((float)v[2] + bb.z);
        r3 += g * ((float)v[3] + bb.w);
    }
    float4 o = make_float4(r0, r1, r2, r3);
    *(float4*)(y + (size_t)n * CDIM + c) = o;
}

// ---------------------------------------------------------------------------
extern "C" void kernel_launch(void* const* d_in, const int* in_sizes, int n_in,
                              void* d_out, int out_size, void* d_ws, size_t ws_size,
                              hipStream_t stream)
{
    const float* x  = (const float*)d_in[0];
    const float* rw = (const float*)d_in[1];
    const float* rb = (const float*)d_in[2];
    const float* w1 = (const float*)d_in[3];
    const float* b1 = (const float*)d_in[4];
    const float* w2 = (const float*)d_in[5];
    const float* b2 = (const float*)d_in[6];
    float* y = (float*)d_out;

    char* ws = (char*)d_ws;
    size_t off = 0;
    auto alloc = [&](size_t bytes) -> void* {
        void* p = ws + off;
        off = (off + bytes + 255) & ~(size_t)255;
        return p;
    };
    __bf16* w1t  = (__bf16*)alloc((size_t)NE * CDIM * HDIM * 2);   // [E][H][C]
    __bf16* w2t  = (__bf16*)alloc((size_t)NE * CDIM * HDIM * 2);   // [E][C][H]
    __bf16* inp  = (__bf16*)alloc((size_t)NE * CAPE * CDIM * 2);   // [E*cap][C]
    __bf16* hbuf = (__bf16*)alloc((size_t)NE * CAPE * HDIM * 2);   // [E*cap][H]
    __bf16* outb = (__bf16*)alloc((size_t)NE * CAPE * CDIM * 2);   // [E*cap][C]
    float*  probs = (float*)alloc((size_t)NTOK * NE * 4);
    float*  gates = (float*)alloc((size_t)NTOK * 2 * 4);
    int*    tidx  = (int*)alloc((size_t)NTOK * 2 * 4);
    int*    slot  = (int*)alloc((size_t)NTOK * 2 * 4);
    int*    tok   = (int*)alloc((size_t)NE * CAPE * 4);

    // 1. prolog: w1 transpose + router
    k_prolog<<<8192 + NTOK / 4, 256, 0, stream>>>(
        w1, x, rw, rb, w1t, probs, gates, tidx);

    // 2. dispatch scan + aux loss (single block, log-scan)
    k_scan<<<1, 256, 0, stream>>>(tidx, probs, slot, tok, y + (size_t)NTOK * CDIM);

    // 3. gather expert inputs (bf16)
    k_gather<<<NE * CAPE, 256, 0, stream>>>(x, tok, inp);

    // 4. fused GEMM1 + w2 transpose
    k_g1w2t<<<G1BLK + 4096, 512, 0, stream>>>(inp, w1t, b1, hbuf, w2, w2t);

    // 5. GEMM2
    k_gemm8<<<dim3((NE * CAPE / 256) * (CDIM / 256)), 512, 0, stream>>>(
        hbuf, w2t, nullptr, outb, HDIM, CDIM, CDIM / 256, CAPE / 256);

    // 6. combine back to tokens (+aux already written by scan)
    k_combine<<<NTOK, 256, 0, stream>>>(outb, slot, gates, tidx, b2, y);
}